// Round 13
// baseline (1368.741 us; speedup 1.0000x reference)
//
#include <hip/hip_runtime.h>
#include <hip/hip_bf16.h>
#include <cstddef>

// ---- problem dims ----
#define Bq    16
#define Lq    512
#define Mq    32
#define PREDq 96
#define Pq    16
#define Sq    8
#define Dq    128
#define NSTq  16
#define DCq   4
#define NLq   4
#define Nq    63
#define DIq   256
#define DTRq  8
#define TOKq  32256   // 512*63 == 1008*32
#define BMq   512
#define BNq   1008

typedef __attribute__((ext_vector_type(8))) short short8;
typedef __attribute__((ext_vector_type(4))) float f32x4;
typedef __attribute__((ext_vector_type(2))) float f32x2;
typedef __hip_bfloat16 bf16;

// ---- workspace layout (float offsets). total 53,804,032 floats = 205.2 MiB ----
constexpr size_t HSZB      = (size_t)TOKq * Dq;              // bf16 elements per hist buf
constexpr size_t OFF_MEANS = 0;
constexpr size_t OFF_STDS  = 512;
constexpr size_t OFF_PART  = 50176;                          // 12*49152 fp32
constexpr size_t OFF_HISTB = 640000;                         // 9 hist bufs, bf16
constexpr size_t OFF_MIX   = OFF_HISTB + 9 * (HSZB / 2);     // fp32 TOK*128
constexpr size_t OFF_XD    = OFF_MIX + (size_t)TOKq * 128;   // fp32 TOK*80
constexpr size_t OFF_XZ2   = OFF_XD + (size_t)TOKq * 80;     // bf16 TOK*1024
constexpr size_t OFF_UC    = OFF_XZ2 + (size_t)TOKq * 512;   // bf16 TOK*512 (conv'd u)
constexpr size_t OFF_LNB   = OFF_UC + (size_t)TOKq * 256;    // bf16 TOK*128
constexpr size_t OFF_WB    = OFF_LNB + (size_t)TOKq * 64;    // bf16 weights
constexpr size_t WS_FLOATS = OFF_WB + 1038336;
// bf16-element offsets inside WB region (contiguous):
constexpr size_t WBE_IN   = 0;           // 12*512*128 = 786432
constexpr size_t WBE_X    = 786432;      // 12*40*256  = 122880
constexpr size_t WBE_OUT  = 909312;      // 12*128*256 = 393216
constexpr size_t WBE_HEAD = 1302528;     // 96*8064    = 774144
constexpr int    WB_TOTAL = 2076672;

__device__ __forceinline__ float silu_f(float v) { return v / (1.f + __expf(-v)); }

// ============ fused fp32 -> bf16 weight conversion ============
__global__ __launch_bounds__(256) void f2b_all(const float* __restrict__ w_in,
                                               const float* __restrict__ w_x,
                                               const float* __restrict__ w_out,
                                               const float* __restrict__ w_head,
                                               bf16* __restrict__ d) {
    int i = blockIdx.x * 256 + threadIdx.x;
    if (i >= WB_TOTAL) return;
    float v;
    if (i < 786432)        v = w_in[i];
    else if (i < 909312)   v = w_x[i - 786432];
    else if (i < 1302528)  v = w_out[i - 909312];
    else                   v = w_head[i - 1302528];
    d[i] = __float2bfloat16(v);
}

// ============ stats ============
__global__ __launch_bounds__(256) void stats_kernel(const float* __restrict__ x,
                                                    float* __restrict__ means,
                                                    float* __restrict__ stds) {
    int bm = blockIdx.x; int b = bm >> 5, m = bm & 31;
    int tid = threadIdx.x;
    float s = 0.f, ss = 0.f;
    for (int l = tid; l < Lq; l += 256) {
        float v = x[((size_t)b * Lq + l) * Mq + m];
        s += v; ss += v * v;
    }
#pragma unroll
    for (int o = 32; o >= 1; o >>= 1) { s += __shfl_xor(s, o); ss += __shfl_xor(ss, o); }
    __shared__ float sh0[4], sh1[4];
    if ((tid & 63) == 0) { sh0[tid >> 6] = s; sh1[tid >> 6] = ss; }
    __syncthreads();
    if (tid == 0) {
        float S  = sh0[0] + sh0[1] + sh0[2] + sh0[3];
        float SS = sh1[0] + sh1[1] + sh1[2] + sh1[3];
        float mean = S * (1.f / (float)Lq);
        float var  = (SS - (float)Lq * mean * mean) * (1.f / (float)(Lq - 1));
        means[bm] = mean;
        stds[bm]  = sqrtf(fmaxf(var, 0.f)) + 1e-5f;
    }
}

// ============ patch embed -> hist[0] (bf16) ============
__global__ __launch_bounds__(128) void patch_embed(const float* __restrict__ x,
                                                   const float* __restrict__ means,
                                                   const float* __restrict__ stds,
                                                   const float* __restrict__ pw,
                                                   const float* __restrict__ pb,
                                                   const float* __restrict__ pos,
                                                   bf16* __restrict__ h) {
    int blk = blockIdx.x;
    int bm = blk / Nq, n = blk - bm * Nq;
    int b = bm >> 5, m = bm & 31;
    int d = threadIdx.x;
    __shared__ float sx[Pq];
    if (d < Pq) {
        int l = n * Sq + d;
        sx[d] = (x[((size_t)b * Lq + l) * Mq + m] - means[bm]) / stds[bm];
    }
    __syncthreads();
    float acc = pb[d];
#pragma unroll
    for (int p = 0; p < Pq; p++) acc += sx[p] * pw[d * Pq + p];
    h[(size_t)blk * Dq + d] = __float2bfloat16(acc + pos[n * Dq + d]);
}

// ============ bf16 MFMA GEMM, templated (same as round 12) ============
template<int CONVM, int KSKIP, int NT>
__global__ __launch_bounds__(256) void gemm_k(
        const bf16* __restrict__ A, int lda,
        const bf16* __restrict__ Bw, const bf16* __restrict__ Bw2, int ldb,
        const float* __restrict__ resid, int ldr,
        float* __restrict__ C, bf16* __restrict__ Cb, int ldc,
        int M, int N, int Klen, int kstride, size_t csplit,
        int accum, int rowmap,
        int slen, const float* __restrict__ cw, const float* __restrict__ cb,
        int Mhalf, int ahalfcol, int choff, int gsilu,
        bf16* __restrict__ ucout) {
    __shared__ __align__(16) short Al[128 * 40];
    __shared__ __align__(16) short Bl[NT * 40];
    __shared__ float scwb[CONVM ? 2560 : 1];
    int tid = threadIdx.x;
    int wave = tid >> 6, lane = tid & 63;
    int m0 = blockIdx.y * 128, n0 = blockIdx.x * NT;
    int kbase = blockIdx.z * kstride;
    int blkhalf = (CONVM == 2) ? (m0 >= Mhalf ? 1 : 0) : 0;
    if (CONVM) {
        int nw = (CONVM == 2) ? 2048 : 1024;
        for (int i = tid; i < nw; i += 256) scwb[i] = cw[i];
        int nb_ = (CONVM == 2) ? 512 : 256;
        for (int i = tid; i < nb_; i += 256) scwb[2048 + i] = cb[i];
        __syncthreads();
    }
    constexpr int NS = NT / 16;
    f32x4 acc[2][NS];
#pragma unroll
    for (int i = 0; i < 2; i++)
#pragma unroll
        for (int j = 0; j < NS; j++) acc[i][j] = (f32x4){0.f, 0.f, 0.f, 0.f};

    int mlane = lane & 15, koff = (lane >> 4) * 8;
    const uint4 Z4 = {0u, 0u, 0u, 0u};

    if (CONVM == 0) {
        int ar = tid >> 1, ah = tid & 1;
        int brr = (NT == 128) ? (tid >> 1) : (tid >> 2);
        int bqh = (NT == 128) ? (tid & 1) : (tid & 3);
        uint4 av0, av1, bv0, bv1;
        av0 = av1 = bv0 = bv1 = Z4;
        auto loadAB = [&](int kk0) {
            int gcol = kk0 + ah * 16;
            if (KSKIP && kk0 >= 256) gcol += 256;
            const bf16* asrc = A + (size_t)(m0 + ar) * lda + gcol;
            av0 = *(const uint4*)asrc;
            av1 = *(const uint4*)(asrc + 8);
            const bf16* bb = Bw;
            if (NT == 128) {
                int bc = kk0 + bqh * 16;
                if (KSKIP && kk0 >= 256) { bb = Bw2; bc -= 256; }
                int gn = n0 + brr;
                if (gn < N) {
                    const bf16* bsrc = bb + (size_t)gn * ldb + bc;
                    bv0 = *(const uint4*)bsrc;
                    bv1 = *(const uint4*)(bsrc + 8);
                } else { bv0 = Z4; bv1 = Z4; }
            } else {
                int bc = kk0 + bqh * 8;
                if (KSKIP && kk0 >= 256) { bb = Bw2; bc -= 256; }
                int gn = n0 + brr;
                bv0 = (gn < N) ? *(const uint4*)(bb + (size_t)gn * ldb + bc) : Z4;
            }
        };
        loadAB(kbase);
        for (int k0 = 0; k0 < Klen; k0 += 32) {
            *(uint4*)&Al[ar * 40 + ah * 16]     = av0;
            *(uint4*)&Al[ar * 40 + ah * 16 + 8] = av1;
            if (NT == 128) {
                *(uint4*)&Bl[brr * 40 + bqh * 16]     = bv0;
                *(uint4*)&Bl[brr * 40 + bqh * 16 + 8] = bv1;
            } else {
                *(uint4*)&Bl[brr * 40 + bqh * 8] = bv0;
            }
            __syncthreads();
            if (k0 + 32 < Klen) loadAB(kbase + k0 + 32);
            short8 a0 = *(const short8*)&Al[(wave * 32 + mlane) * 40 + koff];
            short8 a1 = *(const short8*)&Al[(wave * 32 + 16 + mlane) * 40 + koff];
#pragma unroll
            for (int ns = 0; ns < NS; ns++) {
                short8 bfr = *(const short8*)&Bl[(ns * 16 + mlane) * 40 + koff];
                acc[0][ns] = __builtin_amdgcn_mfma_f32_16x16x32_bf16(a0, bfr, acc[0][ns], 0, 0, 0);
                acc[1][ns] = __builtin_amdgcn_mfma_f32_16x16x32_bf16(a1, bfr, acc[1][ns], 0, 0, 0);
            }
            __syncthreads();
        }
    } else {
        int ar = tid >> 1, ah = tid & 1;
        int br = tid >> 2, bq2 = tid & 3;
        for (int k0 = 0; k0 < Klen; k0 += 32) {
            int kk0 = kbase + k0;
            {
                int t = m0 + ar - blkhalf * Mhalf;
                int s = t % slen;
                int cb0 = kk0 + ah * 16;
                const bf16* arow = A + (size_t)t * lda + blkhalf * ahalfcol + cb0;
                float ac[16];
#pragma unroll
                for (int i = 0; i < 16; i++) ac[i] = scwb[2048 + blkhalf * 256 + cb0 + i];
#pragma unroll
                for (int j = 0; j < 4; j++) {
                    int dj = 3 - j;
                    bool ok = blkhalf ? (s + dj < slen) : (s >= dj);
                    if (ok) {
                        const uint4* p = (const uint4*)(arow + (long)(blkhalf ? dj : -dj) * lda);
                        bf16 tv[16];
                        *(uint4*)&tv[0] = p[0];
                        *(uint4*)&tv[8] = p[1];
#pragma unroll
                        for (int i = 0; i < 16; i++)
                            ac[i] += scwb[blkhalf * 1024 + (cb0 + i) * 4 + j] * __bfloat162float(tv[i]);
                    }
                }
                bf16 ov[16];
#pragma unroll
                for (int i = 0; i < 16; i++) ov[i] = __float2bfloat16(silu_f(ac[i]));
                *(uint4*)&Al[ar * 40 + ah * 16]     = *(uint4*)&ov[0];
                *(uint4*)&Al[ar * 40 + ah * 16 + 8] = *(uint4*)&ov[8];
                bf16* ud = ucout + (size_t)t * 512 + blkhalf * 256 + cb0;
                *(uint4*)ud       = *(uint4*)&ov[0];
                *(uint4*)(ud + 8) = *(uint4*)&ov[8];
            }
            {
                int gn = n0 + br;
                int bc = kk0 + bq2 * 8;
                const bf16* bb = (CONVM == 2 && blkhalf) ? Bw2 : Bw;
                uint4 v = Z4;
                if (gn < N) v = *(const uint4*)(bb + (size_t)gn * ldb + bc);
                *(uint4*)&Bl[br * 40 + bq2 * 8] = v;
            }
            __syncthreads();
            short8 a0 = *(const short8*)&Al[(wave * 32 + mlane) * 40 + koff];
            short8 a1 = *(const short8*)&Al[(wave * 32 + 16 + mlane) * 40 + koff];
#pragma unroll
            for (int ns = 0; ns < NS; ns++) {
                short8 bfr = *(const short8*)&Bl[(ns * 16 + mlane) * 40 + koff];
                acc[0][ns] = __builtin_amdgcn_mfma_f32_16x16x32_bf16(a0, bfr, acc[0][ns], 0, 0, 0);
                acc[1][ns] = __builtin_amdgcn_mfma_f32_16x16x32_bf16(a1, bfr, acc[1][ns], 0, 0, 0);
            }
            __syncthreads();
        }
    }

    float* Cz = C + (size_t)blockIdx.z * csplit;
#pragma unroll
    for (int ms = 0; ms < 2; ms++) {
#pragma unroll
        for (int ns = 0; ns < NS; ns++) {
            int n = n0 + ns * 16 + mlane;
            if (n >= N) continue;
#pragma unroll
            for (int r = 0; r < 4; r++) {
                int m = m0 + wave * 32 + ms * 16 + (lane >> 4) * 4 + r;
                int orow = m, ocol = n;
                if (CONVM == 2) {
                    int hh = (m >= Mhalf) ? 1 : 0;
                    orow = m - hh * Mhalf;
                    ocol = n + hh * choff;
                } else if (rowmap) {
                    int bn = m >> 5, mm = m & 31;
                    int b = bn / Nq, nn = bn - b * Nq;
                    orow = (b * Mq + mm) * Nq + nn;
                }
                float v = acc[ms][ns][r];
                if (resid) v += resid[(size_t)orow * ldr + ocol];
                if (Cb) {
                    if (gsilu && ((ocol >> 8) & 1)) v = silu_f(v);
                    Cb[(size_t)orow * ldc + ocol] = __float2bfloat16(v);
                } else {
                    size_t o = (size_t)orow * ldc + ocol;
                    if (accum) Cz[o] += v; else Cz[o] = v;
                }
            }
        }
    }
}

// ============ out_proj GEMM with fused next-mix+LN epilogue ============
// 512 threads, M-tile 128, NT=128 (N==128 exactly -> full row ownership).
// EPI==1: after out_proj_tok(l): write hist[1+l], then compute mix_ln_ch(l)
//         (weights theta/gamma; self = yT[l+1]); LNB channel-transposed.
// EPI==2: after out_proj_ch(l) (rowmap rows): write hist[5+l], then compute
//         mix_ln_tok(l+1) (alpha/beta; self = yC[l+1]); LNB token layout.
template<int KSKIP, int EPI>
__global__ __launch_bounds__(512) void out_fused(
        const bf16* __restrict__ A,
        const bf16* __restrict__ Bw, const bf16* __restrict__ Bw2,
        const float* __restrict__ MIXr,
        bf16* __restrict__ hist_out,
        const bf16* __restrict__ hb,
        bf16* __restrict__ LNB, float* __restrict__ MIXw,
        const float* __restrict__ w1, const float* __restrict__ w2,
        const float* __restrict__ lnw, const float* __restrict__ lnb,
        int l) {
    __shared__ __align__(16) short Al[128 * 40];
    __shared__ __align__(16) short Bl[128 * 40];
    int tid = threadIdx.x;
    int wave = tid >> 6, lane = tid & 63;
    int mlane = lane & 15, quad = lane >> 4, koff = quad * 8;
    int m0 = blockIdx.y * 128;
    const int Klen = KSKIP ? 512 : 256;
    f32x4 acc[8];
#pragma unroll
    for (int j = 0; j < 8; j++) acc[j] = (f32x4){0.f, 0.f, 0.f, 0.f};

    int ar = tid >> 2, ac8 = (tid & 3) * 8;
    uint4 av, bv;
    auto loadAB = [&](int kk0) {
        int gcol = kk0 + ac8;
        if (KSKIP && kk0 >= 256) gcol += 256;
        av = *(const uint4*)(A + (size_t)(m0 + ar) * 1024 + gcol);
        const bf16* bb = Bw;
        int bc = kk0 + ac8;
        if (KSKIP && kk0 >= 256) { bb = Bw2; bc -= 256; }
        bv = *(const uint4*)(bb + (size_t)ar * 256 + bc);
    };
    loadAB(0);
    for (int k0 = 0; k0 < Klen; k0 += 32) {
        *(uint4*)&Al[ar * 40 + ac8] = av;
        *(uint4*)&Bl[ar * 40 + ac8] = bv;
        __syncthreads();
        if (k0 + 32 < Klen) loadAB(k0 + 32);
        short8 a0 = *(const short8*)&Al[(wave * 16 + mlane) * 40 + koff];
#pragma unroll
        for (int ns = 0; ns < 8; ns++) {
            short8 bfr = *(const short8*)&Bl[(ns * 16 + mlane) * 40 + koff];
            acc[ns] = __builtin_amdgcn_mfma_f32_16x16x32_bf16(a0, bfr, acc[ns], 0, 0, 0);
        }
        __syncthreads();
    }

    // mix softmax weights (per thread, uniform)
    // EPI1: tw over l+2 (theta), gw over l+1 (gamma); self weight = tw[l+1]
    // EPI2: lm=l+1; aw,bw over lm+1 (alpha,beta); self weight = bw[lm]
    int lm = (EPI == 2) ? (l + 1) : l;
    int n1 = (EPI == 1) ? (l + 2) : (lm + 1);   // yT-weight count
    int n2 = (EPI == 1) ? (l + 1) : (lm + 1);   // yC-weight count
    float w1v[5], w2v[5];
    {
        int base1 = (EPI == 1) ? (l * 5) : (lm * 4);
        int base2 = (EPI == 1) ? (l * 4) : (lm * 4);
        float m1 = -1e30f, m2 = -1e30f;
        for (int i = 0; i < n1; i++) { w1v[i] = w1[base1 + i]; m1 = fmaxf(m1, w1v[i]); }
        for (int i = 0; i < n2; i++) { w2v[i] = w2[base2 + i]; m2 = fmaxf(m2, w2v[i]); }
        float s1 = 0.f, s2 = 0.f;
        for (int i = 0; i < n1; i++) { w1v[i] = __expf(w1v[i] - m1); s1 += w1v[i]; }
        for (int i = 0; i < n2; i++) { w2v[i] = __expf(w2v[i] - m2); s2 += w2v[i]; }
        float i1 = 1.f / s1, i2 = 1.f / s2;
        for (int i = 0; i < n1; i++) w1v[i] *= i1;
        for (int i = 0; i < n2; i++) w2v[i] *= i2;
    }

#pragma unroll
    for (int r = 0; r < 4; r++) {
        int m = m0 + wave * 16 + quad * 4 + r;
        int orow = m;
        if (EPI == 2) {                          // channel->token rowmap
            int bn = m >> 5, mm = m & 31;
            int b = bn / Nq, nn = bn - b * Nq;
            orow = (b * Mq + mm) * Nq + nn;
        }
        float vmix[8];
#pragma unroll
        for (int ns = 0; ns < 8; ns++) {
            int ocol = ns * 16 + mlane;
            size_t off = (size_t)orow * 128 + ocol;
            float v = acc[ns][r] + MIXr[off];
            hist_out[off] = __float2bfloat16(v);
            float vm;
            if (EPI == 1) {
                // mix_ln_ch(l): sum tw[i]*yT[i] (i=0..l+1, self=l+1) + gw[i]*yC[i] (i=0..l)
                vm = w1v[l + 1] * v;
                for (int i = 0; i <= l; i++) {
                    vm += w1v[i] * __bfloat162float(hb[(size_t)(i == 0 ? 0 : i) * HSZB + off]);
                    vm += w2v[i] * __bfloat162float(hb[(size_t)(i == 0 ? 0 : 4 + i) * HSZB + off]);
                }
            } else {
                // mix_ln_tok(lm): sum aw[i]*yT[i] + bw[i]*yC[i], i=0..lm; self = yC[lm]=v
                vm = w2v[lm] * v;
                for (int i = 0; i <= lm; i++) {
                    vm += w1v[i] * __bfloat162float(hb[(size_t)(i == 0 ? 0 : i) * HSZB + off]);
                    if (i < lm)
                        vm += w2v[i] * __bfloat162float(hb[(size_t)(i == 0 ? 0 : 4 + i) * HSZB + off]);
                }
            }
            vmix[ns] = vm;
        }
        // row stats over 128 cols: in-lane over 8 ns + 16-lane shuffle
        float s = 0.f, ss = 0.f;
#pragma unroll
        for (int ns = 0; ns < 8; ns++) { s += vmix[ns]; ss += vmix[ns] * vmix[ns]; }
#pragma unroll
        for (int o = 8; o >= 1; o >>= 1) { s += __shfl_xor(s, o); ss += __shfl_xor(ss, o); }
        float mean = s * (1.f / 128.f);
        float var  = ss * (1.f / 128.f) - mean * mean;
        float rstd = rsqrtf(var + 1e-5f);
        // LNB destination row
        size_t lrow;
        if (EPI == 1) {                          // channel-transposed
            int bm = orow / Nq, nn = orow - bm * Nq, b = bm >> 5, mm = bm & 31;
            lrow = (size_t)((b * Nq + nn) * Mq + mm);
        } else {
            lrow = (size_t)orow;
        }
#pragma unroll
        for (int ns = 0; ns < 8; ns++) {
            int ocol = ns * 16 + mlane;
            MIXw[(size_t)orow * 128 + ocol] = vmix[ns];
            float lnv = (vmix[ns] - mean) * rstd * lnw[ocol] + lnb[ocol];
            LNB[lrow * 128 + ocol] = __float2bfloat16(lnv);
        }
    }
}

// ============ fused dt_proj + softplus + scan + D skip + gate ============
template<int SLEN>
__global__ __launch_bounds__(256) void scan_k(bf16* __restrict__ xz2,
                                              const bf16* __restrict__ uc,
                                              const float* __restrict__ xd, int ldxd,
                                              const float* __restrict__ dtw,
                                              const float* __restrict__ dtb,
                                              const float* __restrict__ alog,
                                              const float* __restrict__ Dp,
                                              int nb, int dual) {
    int bid = blockIdx.x;
    int half = (dual && bid >= nb) ? 1 : 0;
    int row = bid - half * nb;
    int rev = half;
    int d = threadIdx.x;
    f32x2 h2[8];
#pragma unroll
    for (int j = 0; j < 8; j++) h2[j] = (f32x2){0.f, 0.f};
    const float* al = alog + half * 4096 + d * 16;
    float a0 = -__expf(al[0]);
    bool fast = true;
#pragma unroll
    for (int j = 1; j < 16; j++) {
        float aj = -__expf(al[j]);
        fast = fast && (fabsf(aj - a0 * (float)(j + 1)) < 1e-5f * (float)(j + 1));
    }
    f32x2 dw2[4];
#pragma unroll
    for (int r = 0; r < 4; r++)
        dw2[r] = (f32x2){dtw[half * 2048 + d * 8 + 2 * r], dtw[half * 2048 + d * 8 + 2 * r + 1]};
    float dbv = dtb[half * 256 + d], Dv = Dp[half * 256 + d];

    const float* xr = xd + (size_t)row * SLEN * ldxd + half * 40;
    size_t base  = (size_t)row * SLEN * 1024 + half * 512 + d;
    size_t ubase = (size_t)row * SLEN * 512 + half * 256 + d;
    constexpr int NCH = (SLEN + 7) / 8;
    int dstep = rev ? -1 : 1;

    float ucur[8], zcur[8], unxt[8], znxt[8];
#pragma unroll
    for (int i = 0; i < 8; i++) {
        int st = i < SLEN ? i : SLEN - 1;
        int s = rev ? (SLEN - 1 - st) : st;
        ucur[i] = __bfloat162float(uc[ubase + (size_t)s * 512]);
        zcur[i] = __bfloat162float(xz2[base + (size_t)s * 1024 + 256]);
    }
    float qb[2][40];
    {
        const float4* p = (const float4*)(xr + (size_t)(rev ? (SLEN - 1) : 0) * ldxd);
#pragma unroll
        for (int k = 0; k < 10; k++) *(float4*)&qb[0][k * 4] = p[k];
    }

    for (int c = 0; c < NCH; c++) {
        if (c + 1 < NCH) {
#pragma unroll
            for (int i = 0; i < 8; i++) {
                int st = (c + 1) * 8 + i; st = st < SLEN ? st : SLEN - 1;
                int s = rev ? (SLEN - 1 - st) : st;
                unxt[i] = __bfloat162float(uc[ubase + (size_t)s * 512]);
                znxt[i] = __bfloat162float(xz2[base + (size_t)s * 1024 + 256]);
            }
        }
#pragma unroll
        for (int i = 0; i < 8; i++) {
            int st = c * 8 + i;
            if (st < SLEN) {
                int s = rev ? (SLEN - 1 - st) : st;
                const float* q = qb[i & 1];
                if (st + 1 < SLEN) {
                    const float4* p = (const float4*)(xr + (size_t)(s + dstep) * ldxd);
#pragma unroll
                    for (int k = 0; k < 10; k++) *(float4*)&qb[(i + 1) & 1][k * 4] = p[k];
                }
                float uc_v = ucur[i];
                f32x2 acc2 = dw2[0] * (f32x2){q[0], q[1]};
                acc2 += dw2[1] * (f32x2){q[2], q[3]};
                acc2 += dw2[2] * (f32x2){q[4], q[5]};
                acc2 += dw2[3] * (f32x2){q[6], q[7]};
                float dtv = dbv + acc2.x + acc2.y;
                dtv = fmaxf(dtv, 0.f) + __logf(1.f + __expf(-fabsf(dtv)));
                float du = dtv * uc_v;
                float y;
                if (fast) {
                    float p1 = __expf(dtv * a0);
                    float p2 = p1 * p1;
                    f32x2 pp = (f32x2){p2, p2};
                    f32x2 e2[8];
                    e2[0] = (f32x2){p1, p2};
#pragma unroll
                    for (int j = 1; j < 8; j++) e2[j] = e2[j - 1] * pp;
                    f32x2 du2 = (f32x2){du, du};
                    f32x2 y2 = (f32x2){0.f, 0.f};
#pragma unroll
                    for (int j = 0; j < 8; j++) {
                        f32x2 b2 = (f32x2){q[8 + 2 * j], q[9 + 2 * j]};
                        f32x2 c2 = (f32x2){q[24 + 2 * j], q[25 + 2 * j]};
                        h2[j] = h2[j] * e2[j] + du2 * b2;
                        y2 += h2[j] * c2;
                    }
                    y = y2.x + y2.y;
                } else {
                    y = 0.f;
#pragma unroll
                    for (int j = 0; j < 16; j++) {
                        float e = __expf(dtv * (-__expf(al[j])));
                        float hh = h2[j >> 1][j & 1];
                        hh = hh * e + du * q[8 + j];
                        h2[j >> 1][j & 1] = hh;
                        y += hh * q[24 + j];
                    }
                }
                xz2[base + (size_t)s * 1024] =
                    __float2bfloat16((y + uc_v * Dv) * zcur[i]);
            }
        }
#pragma unroll
        for (int i = 0; i < 8; i++) { ucur[i] = unxt[i]; zcur[i] = znxt[i]; }
    }
}

// ============ token mix + LN (standalone, only for l=0) ============
__global__ __launch_bounds__(256) void mix_ln_tok(const bf16* __restrict__ hb,
                                                 float* __restrict__ mixb, bf16* __restrict__ lnb_out,
                                                 const float* __restrict__ alpha,
                                                 const float* __restrict__ beta,
                                                 const float* __restrict__ lnw,
                                                 const float* __restrict__ lnb, int l) {
    int t = blockIdx.x * 4 + (threadIdx.x >> 6), d = threadIdx.x & 63;
    int cnt = l + 1;
    float aw[4], bw[4];
    float amax = -1e30f, bmax = -1e30f;
    for (int i = 0; i < cnt; i++) {
        aw[i] = alpha[l * 4 + i]; bw[i] = beta[l * 4 + i];
        amax = fmaxf(amax, aw[i]); bmax = fmaxf(bmax, bw[i]);
    }
    float as = 0.f, bs = 0.f;
    for (int i = 0; i < cnt; i++) {
        aw[i] = __expf(aw[i] - amax); as += aw[i];
        bw[i] = __expf(bw[i] - bmax); bs += bw[i];
    }
    float ai = 1.f / as, bi = 1.f / bs;
    float v0 = 0.f, v1 = 0.f;
    for (int i = 0; i < cnt; i++) {
        const bf16* yt = hb + (size_t)(i == 0 ? 0 : i) * HSZB + (size_t)t * 128;
        const bf16* yc = hb + (size_t)(i == 0 ? 0 : 4 + i) * HSZB + (size_t)t * 128;
        float wa = aw[i] * ai, wb = bw[i] * bi;
        v0 += wa * __bfloat162float(yt[d])      + wb * __bfloat162float(yc[d]);
        v1 += wa * __bfloat162float(yt[d + 64]) + wb * __bfloat162float(yc[d + 64]);
    }
    float* mix = mixb + (size_t)t * 128;
    mix[d] = v0; mix[d + 64] = v1;
    float s = v0 + v1, ss = v0 * v0 + v1 * v1;
#pragma unroll
    for (int o = 32; o >= 1; o >>= 1) { s += __shfl_xor(s, o); ss += __shfl_xor(ss, o); }
    float mean = s * (1.f / 128.f);
    float var  = ss * (1.f / 128.f) - mean * mean;
    float rstd = rsqrtf(var + 1e-5f);
    bf16* lo = lnb_out + (size_t)t * 128;
    lo[d]      = __float2bfloat16((v0 - mean) * rstd * lnw[d]      + lnb[d]);
    lo[d + 64] = __float2bfloat16((v1 - mean) * rstd * lnw[d + 64] + lnb[d + 64]);
}

// ============ plain LN over D=128 (bf16 in, fp32 out, 4 rows/block) ============
__global__ __launch_bounds__(256) void ln128_kernel(const bf16* __restrict__ in,
                                                   const float* __restrict__ w,
                                                   const float* __restrict__ b,
                                                   float* __restrict__ out) {
    int t = blockIdx.x * 4 + (threadIdx.x >> 6), d = threadIdx.x & 63;
    float v0 = __bfloat162float(in[(size_t)t * 128 + d]);
    float v1 = __bfloat162float(in[(size_t)t * 128 + d + 64]);
    float s = v0 + v1, ss = v0 * v0 + v1 * v1;
#pragma unroll
    for (int o = 32; o >= 1; o >>= 1) { s += __shfl_xor(s, o); ss += __shfl_xor(ss, o); }
    float mean = s * (1.f / 128.f);
    float var  = ss * (1.f / 128.f) - mean * mean;
    float rstd = rsqrtf(var + 1e-5f);
    out[(size_t)t * 128 + d]      = (v0 - mean) * rstd * w[d]      + b[d];
    out[(size_t)t * 128 + d + 64] = (v1 - mean) * rstd * w[d + 64] + b[d + 64];
}

// ============ LN over N=63, bf16 out ============
__global__ __launch_bounds__(256) void final_ln2(const float* __restrict__ in,
                                                 const float* __restrict__ w2,
                                                 const float* __restrict__ b2,
                                                 bf16* __restrict__ out) {
    int idx = blockIdx.x * 256 + threadIdx.x;
    if (idx >= BMq * Dq) return;
    int bm = idx >> 7, d = idx & 127;
    float s = 0.f, ss = 0.f;
    for (int n = 0; n < Nq; n++) {
        float v = in[((size_t)bm * Nq + n) * 128 + d];
        s += v; ss += v * v;
    }
    float mean = s * (1.f / (float)Nq);
    float var  = ss * (1.f / (float)Nq) - mean * mean;
    float rstd = rsqrtf(var + 1e-5f);
    for (int n = 0; n < Nq; n++) {
        float v = in[((size_t)bm * Nq + n) * 128 + d];
        out[((size_t)bm * Nq + n) * 128 + d] = __float2bfloat16((v - mean) * rstd * w2[n] + b2[n]);
    }
}

// ============ final: split-K reduce + bias + rescale + transpose ============
__global__ __launch_bounds__(256) void finalize_kernel(const float* __restrict__ part,
                                                       const float* __restrict__ bias,
                                                       const float* __restrict__ means,
                                                       const float* __restrict__ stds,
                                                       float* __restrict__ out) {
    int idx = blockIdx.x * 256 + threadIdx.x;
    if (idx >= Bq * PREDq * Mq) return;
    int b = idx / (PREDq * Mq);
    int r = idx - b * PREDq * Mq;
    int pr = r >> 5, m = r & 31;
    int bm = b * Mq + m;
    float s = bias[pr];
#pragma unroll
    for (int z = 0; z < 12; z++) s += part[(size_t)z * BMq * PREDq + (size_t)bm * PREDq + pr];
    out[idx] = s * stds[bm] + means[bm];
}

extern "C" void kernel_launch(void* const* d_in, const int* in_sizes, int n_in,
                              void* d_out, int out_size, void* d_ws, size_t ws_size,
                              hipStream_t stream) {
    if (ws_size < WS_FLOATS * sizeof(float)) return;

    const float* x          = (const float*)d_in[0];
    const float* patch_w    = (const float*)d_in[1];
    const float* patch_b    = (const float*)d_in[2];
    const float* pos_embed  = (const float*)d_in[3];
    const float* alpha      = (const float*)d_in[4];
    const float* beta       = (const float*)d_in[5];
    const float* theta      = (const float*)d_in[6];
    const float* gamma      = (const float*)d_in[7];
    const float* tok_norm_w = (const float*)d_in[8];
    const float* tok_norm_b = (const float*)d_in[9];
    const float* ch_norm_w  = (const float*)d_in[10];
    const float* ch_norm_b  = (const float*)d_in[11];
    const float* in_proj_w  = (const float*)d_in[12];
    const float* conv_w     = (const float*)d_in[13];
    const float* conv_b     = (const float*)d_in[14];
    const float* x_proj_w   = (const float*)d_in[15];
    const float* dt_proj_w  = (const float*)d_in[16];
    const float* dt_proj_b  = (const float*)d_in[17];
    const float* A_log      = (const float*)d_in[18];
    const float* D_ssm      = (const float*)d_in[19];
    const float* out_proj_w = (const float*)d_in[20];
    const float* n2d_w1     = (const float*)d_in[21];
    const float* n2d_b1     = (const float*)d_in[22];
    const float* n2d_w2     = (const float*)d_in[23];
    const float* n2d_b2     = (const float*)d_in[24];
    const float* head_w     = (const float*)d_in[25];
    const float* head_b     = (const float*)d_in[26];

    float* W   = (float*)d_ws;
    float* out = (float*)d_out;
    bf16* WB   = (bf16*)(W + OFF_WB);
    bf16* HB   = (bf16*)(W + OFF_HISTB);
    bf16* LNB  = (bf16*)(W + OFF_LNB);
    bf16* XZ2  = (bf16*)(W + OFF_XZ2);
    bf16* UC   = (bf16*)(W + OFF_UC);
    float* XD  = W + OFF_XD;
    float* MIX = W + OFF_MIX;

    f2b_all<<<(WB_TOTAL + 255) / 256, 256, 0, stream>>>(
        in_proj_w, x_proj_w, out_proj_w, head_w, WB);

    stats_kernel<<<BMq, 256, 0, stream>>>(x, W + OFF_MEANS, W + OFF_STDS);
    patch_embed<<<TOKq, 128, 0, stream>>>(x, W + OFF_MEANS, W + OFF_STDS,
                                          patch_w, patch_b, pos_embed, HB);

    for (int l = 0; l < NLq; l++) {
        size_t o0 = (size_t)(l * 3 + 0), o1 = (size_t)(l * 3 + 1), o2 = (size_t)(l * 3 + 2);

        // ================= token mamba =================
        if (l == 0)
            mix_ln_tok<<<TOKq / 4, 256, 0, stream>>>(HB, MIX, LNB, alpha, beta,
                                                     tok_norm_w, tok_norm_b, 0);
        gemm_k<0, 0, 128><<<dim3(4, 252, 1), 256, 0, stream>>>(
            LNB, 128, WB + WBE_IN + o0 * 65536, nullptr, 128, nullptr, 0,
            nullptr, XZ2, 1024, TOKq, 512, 128, 0, 0, 0, 0,
            0, nullptr, nullptr, 0, 0, 0, 1, nullptr);
        gemm_k<1, 0, 64><<<dim3(1, 252, 1), 256, 0, stream>>>(
            XZ2, 1024, WB + WBE_X + o0 * 10240, nullptr, 256, nullptr, 0,
            XD, nullptr, 40, TOKq, 40, 256, 0, 0, 0, 0,
            Nq, conv_w + o0 * 1024, conv_b + o0 * 256, 0, 0, 0, 0, UC);
        scan_k<Nq><<<BMq, 256, 0, stream>>>(
            XZ2, UC, XD, 40, dt_proj_w + o0 * 2048, dt_proj_b + o0 * 256,
            A_log + o0 * 4096, D_ssm + o0 * 256, BMq, 0);
        // out_proj_tok + fused mix_ln_ch(l)
        out_fused<0, 1><<<dim3(1, 252, 1), 512, 0, stream>>>(
            XZ2, WB + WBE_OUT + o0 * 32768, nullptr, MIX,
            HB + (size_t)(1 + l) * HSZB, HB, LNB, MIX,
            theta, gamma, ch_norm_w + l * Dq, ch_norm_b + l * Dq, l);

        // ================= channel mamba (fwd+bwd merged) =================
        gemm_k<0, 0, 128><<<dim3(8, 252, 1), 256, 0, stream>>>(
            LNB, 128, WB + WBE_IN + o1 * 65536, nullptr, 128, nullptr, 0,
            nullptr, XZ2, 1024, TOKq, 1024, 128, 0, 0, 0, 0,
            0, nullptr, nullptr, 0, 0, 0, 1, nullptr);
        gemm_k<2, 0, 64><<<dim3(1, 504, 1), 256, 0, stream>>>(
            XZ2, 1024, WB + WBE_X + o1 * 10240, WB + WBE_X + o2 * 10240, 256,
            nullptr, 0, XD, nullptr, 80, 2 * TOKq, 40, 256, 0, 0, 0, 0,
            Mq, conv_w + o1 * 1024, conv_b + o1 * 256, TOKq, 512, 40, 0, UC);
        scan_k<Mq><<<2 * BNq, 256, 0, stream>>>(
            XZ2, UC, XD, 80, dt_proj_w + o1 * 2048, dt_proj_b + o1 * 256,
            A_log + o1 * 4096, D_ssm + o1 * 256, BNq, 1);
        if (l < NLq - 1) {
            // out_proj_ch + fused mix_ln_tok(l+1)
            out_fused<1, 2><<<dim3(1, 252, 1), 512, 0, stream>>>(
                XZ2, WB + WBE_OUT + o1 * 32768, WB + WBE_OUT + o2 * 32768, MIX,
                HB + (size_t)(5 + l) * HSZB, HB, LNB, MIX,
                alpha, beta, tok_norm_w + (l + 1) * Dq, tok_norm_b + (l + 1) * Dq, l);
        } else {
            gemm_k<0, 1, 64><<<dim3(2, 252, 1), 256, 0, stream>>>(
                XZ2, 1024, WB + WBE_OUT + o1 * 32768, WB + WBE_OUT + o2 * 32768, 256,
                MIX, 128, nullptr, HB + (size_t)(5 + l) * HSZB, 128,
                TOKq, 128, 512, 0, 0, 0, 1, 0, nullptr, nullptr, 0, 0, 0, 0, nullptr);
        }
    }

    // ---- Norm2D + head ----
    ln128_kernel<<<TOKq / 4, 256, 0, stream>>>(HB + 8 * HSZB, n2d_w1, n2d_b1, MIX);
    final_ln2<<<(BMq * Dq + 255) / 256, 256, 0, stream>>>(MIX, n2d_w2, n2d_b2, LNB);
    gemm_k<0, 0, 64><<<dim3(2, 4, 12), 256, 0, stream>>>(
        LNB, Nq * Dq, WB + WBE_HEAD, nullptr, Nq * Dq, nullptr, 0,
        W + OFF_PART, nullptr, PREDq, BMq, PREDq, 672, 672,
        (size_t)BMq * PREDq, 0, 0, 0, nullptr, nullptr, 0, 0, 0, 0, nullptr);
    finalize_kernel<<<(Bq * PREDq * Mq + 255) / 256, 256, 0, stream>>>(
        W + OFF_PART, head_b, W + OFF_MEANS, W + OFF_STDS, out);
}

// Round 14
// 1302.922 us; speedup vs baseline: 1.0505x; 1.0505x over previous
//
#include <hip/hip_runtime.h>
#include <hip/hip_bf16.h>
#include <cstddef>

// ---- problem dims ----
#define Bq    16
#define Lq    512
#define Mq    32
#define PREDq 96
#define Pq    16
#define Sq    8
#define Dq    128
#define NSTq  16
#define DCq   4
#define NLq   4
#define Nq    63
#define DIq   256
#define DTRq  8
#define TOKq  32256   // 512*63 == 1008*32
#define BMq   512
#define BNq   1008

typedef __attribute__((ext_vector_type(8))) short short8;
typedef __attribute__((ext_vector_type(4))) float f32x4;
typedef __attribute__((ext_vector_type(2))) float f32x2;
typedef __hip_bfloat16 bf16;

// ---- workspace layout (float offsets). total 53,804,032 floats = 205.2 MiB ----
constexpr size_t HSZB      = (size_t)TOKq * Dq;              // bf16 elements per hist buf
constexpr size_t OFF_MEANS = 0;
constexpr size_t OFF_STDS  = 512;
constexpr size_t OFF_PART  = 50176;                          // 12*49152 fp32
constexpr size_t OFF_HISTB = 640000;                         // 9 hist bufs, bf16
constexpr size_t OFF_MIX   = OFF_HISTB + 9 * (HSZB / 2);     // fp32 TOK*128
constexpr size_t OFF_XD    = OFF_MIX + (size_t)TOKq * 128;   // fp32 TOK*80
constexpr size_t OFF_XZ2   = OFF_XD + (size_t)TOKq * 80;     // bf16 TOK*1024
constexpr size_t OFF_UC    = OFF_XZ2 + (size_t)TOKq * 512;   // bf16 TOK*512 (conv'd u)
constexpr size_t OFF_LNB   = OFF_UC + (size_t)TOKq * 256;    // bf16 TOK*128
constexpr size_t OFF_WB    = OFF_LNB + (size_t)TOKq * 64;    // bf16 weights
constexpr size_t WS_FLOATS = OFF_WB + 1038336;
// bf16-element offsets inside WB region (contiguous):
constexpr size_t WBE_IN   = 0;           // 12*512*128 = 786432
constexpr size_t WBE_X    = 786432;      // 12*40*256  = 122880
constexpr size_t WBE_OUT  = 909312;      // 12*128*256 = 393216
constexpr size_t WBE_HEAD = 1302528;     // 96*8064    = 774144
constexpr int    WB_TOTAL = 2076672;

__device__ __forceinline__ float silu_f(float v) { return v / (1.f + __expf(-v)); }

// ============ fused fp32 -> bf16 weight conversion ============
__global__ __launch_bounds__(256) void f2b_all(const float* __restrict__ w_in,
                                               const float* __restrict__ w_x,
                                               const float* __restrict__ w_out,
                                               const float* __restrict__ w_head,
                                               bf16* __restrict__ d) {
    int i = blockIdx.x * 256 + threadIdx.x;
    if (i >= WB_TOTAL) return;
    float v;
    if (i < 786432)        v = w_in[i];
    else if (i < 909312)   v = w_x[i - 786432];
    else if (i < 1302528)  v = w_out[i - 909312];
    else                   v = w_head[i - 1302528];
    d[i] = __float2bfloat16(v);
}

// ============ stats ============
__global__ __launch_bounds__(256) void stats_kernel(const float* __restrict__ x,
                                                    float* __restrict__ means,
                                                    float* __restrict__ stds) {
    int bm = blockIdx.x; int b = bm >> 5, m = bm & 31;
    int tid = threadIdx.x;
    float s = 0.f, ss = 0.f;
    for (int l = tid; l < Lq; l += 256) {
        float v = x[((size_t)b * Lq + l) * Mq + m];
        s += v; ss += v * v;
    }
#pragma unroll
    for (int o = 32; o >= 1; o >>= 1) { s += __shfl_xor(s, o); ss += __shfl_xor(ss, o); }
    __shared__ float sh0[4], sh1[4];
    if ((tid & 63) == 0) { sh0[tid >> 6] = s; sh1[tid >> 6] = ss; }
    __syncthreads();
    if (tid == 0) {
        float S  = sh0[0] + sh0[1] + sh0[2] + sh0[3];
        float SS = sh1[0] + sh1[1] + sh1[2] + sh1[3];
        float mean = S * (1.f / (float)Lq);
        float var  = (SS - (float)Lq * mean * mean) * (1.f / (float)(Lq - 1));
        means[bm] = mean;
        stds[bm]  = sqrtf(fmaxf(var, 0.f)) + 1e-5f;
    }
}

// ============ patch embed -> hist[0] (bf16) ============
__global__ __launch_bounds__(128) void patch_embed(const float* __restrict__ x,
                                                   const float* __restrict__ means,
                                                   const float* __restrict__ stds,
                                                   const float* __restrict__ pw,
                                                   const float* __restrict__ pb,
                                                   const float* __restrict__ pos,
                                                   bf16* __restrict__ h) {
    int blk = blockIdx.x;
    int bm = blk / Nq, n = blk - bm * Nq;
    int b = bm >> 5, m = bm & 31;
    int d = threadIdx.x;
    __shared__ float sx[Pq];
    if (d < Pq) {
        int l = n * Sq + d;
        sx[d] = (x[((size_t)b * Lq + l) * Mq + m] - means[bm]) / stds[bm];
    }
    __syncthreads();
    float acc = pb[d];
#pragma unroll
    for (int p = 0; p < Pq; p++) acc += sx[p] * pw[d * Pq + p];
    h[(size_t)blk * Dq + d] = __float2bfloat16(acc + pos[n * Dq + d]);
}

// ============ bf16 MFMA GEMM, templated ============
// CONVM==0: register double-buffered pipeline. CONVM>0: conv-on-A staging;
// also writes the conv'd+silu'd A elements to UC (each staged exactly once).
// gsilu: bf16 epilogue applies silu to cols with bit8 set (z columns).
template<int CONVM, int KSKIP, int NT>
__global__ __launch_bounds__(256) void gemm_k(
        const bf16* __restrict__ A, int lda,
        const bf16* __restrict__ Bw, const bf16* __restrict__ Bw2, int ldb,
        const float* __restrict__ resid, int ldr,
        float* __restrict__ C, bf16* __restrict__ Cb, int ldc,
        int M, int N, int Klen, int kstride, size_t csplit,
        int accum, int rowmap,
        int slen, const float* __restrict__ cw, const float* __restrict__ cb,
        int Mhalf, int ahalfcol, int choff, int gsilu,
        bf16* __restrict__ ucout) {
    __shared__ __align__(16) short Al[128 * 40];
    __shared__ __align__(16) short Bl[NT * 40];
    __shared__ float scwb[CONVM ? 2560 : 1];
    int tid = threadIdx.x;
    int wave = tid >> 6, lane = tid & 63;
    int m0 = blockIdx.y * 128, n0 = blockIdx.x * NT;
    int kbase = blockIdx.z * kstride;
    int blkhalf = (CONVM == 2) ? (m0 >= Mhalf ? 1 : 0) : 0;
    if (CONVM) {
        int nw = (CONVM == 2) ? 2048 : 1024;
        for (int i = tid; i < nw; i += 256) scwb[i] = cw[i];
        int nb_ = (CONVM == 2) ? 512 : 256;
        for (int i = tid; i < nb_; i += 256) scwb[2048 + i] = cb[i];
        __syncthreads();
    }
    constexpr int NS = NT / 16;
    f32x4 acc[2][NS];
#pragma unroll
    for (int i = 0; i < 2; i++)
#pragma unroll
        for (int j = 0; j < NS; j++) acc[i][j] = (f32x4){0.f, 0.f, 0.f, 0.f};

    int mlane = lane & 15, koff = (lane >> 4) * 8;
    const uint4 Z4 = {0u, 0u, 0u, 0u};

    if (CONVM == 0) {
        int ar = tid >> 1, ah = tid & 1;
        int brr = (NT == 128) ? (tid >> 1) : (tid >> 2);
        int bqh = (NT == 128) ? (tid & 1) : (tid & 3);
        uint4 av0, av1, bv0, bv1;
        av0 = av1 = bv0 = bv1 = Z4;
        auto loadAB = [&](int kk0) {
            int gcol = kk0 + ah * 16;
            if (KSKIP && kk0 >= 256) gcol += 256;
            const bf16* asrc = A + (size_t)(m0 + ar) * lda + gcol;
            av0 = *(const uint4*)asrc;
            av1 = *(const uint4*)(asrc + 8);
            const bf16* bb = Bw;
            if (NT == 128) {
                int bc = kk0 + bqh * 16;
                if (KSKIP && kk0 >= 256) { bb = Bw2; bc -= 256; }
                int gn = n0 + brr;
                if (gn < N) {
                    const bf16* bsrc = bb + (size_t)gn * ldb + bc;
                    bv0 = *(const uint4*)bsrc;
                    bv1 = *(const uint4*)(bsrc + 8);
                } else { bv0 = Z4; bv1 = Z4; }
            } else {
                int bc = kk0 + bqh * 8;
                if (KSKIP && kk0 >= 256) { bb = Bw2; bc -= 256; }
                int gn = n0 + brr;
                bv0 = (gn < N) ? *(const uint4*)(bb + (size_t)gn * ldb + bc) : Z4;
            }
        };
        loadAB(kbase);
        for (int k0 = 0; k0 < Klen; k0 += 32) {
            *(uint4*)&Al[ar * 40 + ah * 16]     = av0;
            *(uint4*)&Al[ar * 40 + ah * 16 + 8] = av1;
            if (NT == 128) {
                *(uint4*)&Bl[brr * 40 + bqh * 16]     = bv0;
                *(uint4*)&Bl[brr * 40 + bqh * 16 + 8] = bv1;
            } else {
                *(uint4*)&Bl[brr * 40 + bqh * 8] = bv0;
            }
            __syncthreads();
            if (k0 + 32 < Klen) loadAB(kbase + k0 + 32);
            short8 a0 = *(const short8*)&Al[(wave * 32 + mlane) * 40 + koff];
            short8 a1 = *(const short8*)&Al[(wave * 32 + 16 + mlane) * 40 + koff];
#pragma unroll
            for (int ns = 0; ns < NS; ns++) {
                short8 bfr = *(const short8*)&Bl[(ns * 16 + mlane) * 40 + koff];
                acc[0][ns] = __builtin_amdgcn_mfma_f32_16x16x32_bf16(a0, bfr, acc[0][ns], 0, 0, 0);
                acc[1][ns] = __builtin_amdgcn_mfma_f32_16x16x32_bf16(a1, bfr, acc[1][ns], 0, 0, 0);
            }
            __syncthreads();
        }
    } else {
        int ar = tid >> 1, ah = tid & 1;
        int br = tid >> 2, bq2 = tid & 3;
        for (int k0 = 0; k0 < Klen; k0 += 32) {
            int kk0 = kbase + k0;
            {
                int t = m0 + ar - blkhalf * Mhalf;
                int s = t % slen;
                int cb0 = kk0 + ah * 16;
                const bf16* arow = A + (size_t)t * lda + blkhalf * ahalfcol + cb0;
                float ac[16];
#pragma unroll
                for (int i = 0; i < 16; i++) ac[i] = scwb[2048 + blkhalf * 256 + cb0 + i];
#pragma unroll
                for (int j = 0; j < 4; j++) {
                    int dj = 3 - j;
                    bool ok = blkhalf ? (s + dj < slen) : (s >= dj);
                    if (ok) {
                        const uint4* p = (const uint4*)(arow + (long)(blkhalf ? dj : -dj) * lda);
                        bf16 tv[16];
                        *(uint4*)&tv[0] = p[0];
                        *(uint4*)&tv[8] = p[1];
#pragma unroll
                        for (int i = 0; i < 16; i++)
                            ac[i] += scwb[blkhalf * 1024 + (cb0 + i) * 4 + j] * __bfloat162float(tv[i]);
                    }
                }
                bf16 ov[16];
#pragma unroll
                for (int i = 0; i < 16; i++) ov[i] = __float2bfloat16(silu_f(ac[i]));
                *(uint4*)&Al[ar * 40 + ah * 16]     = *(uint4*)&ov[0];
                *(uint4*)&Al[ar * 40 + ah * 16 + 8] = *(uint4*)&ov[8];
                // persist conv'd u for the scan (each element staged exactly once)
                bf16* ud = ucout + (size_t)t * 512 + blkhalf * 256 + cb0;
                *(uint4*)ud       = *(uint4*)&ov[0];
                *(uint4*)(ud + 8) = *(uint4*)&ov[8];
            }
            {
                int gn = n0 + br;
                int bc = kk0 + bq2 * 8;
                const bf16* bb = (CONVM == 2 && blkhalf) ? Bw2 : Bw;
                uint4 v = Z4;
                if (gn < N) v = *(const uint4*)(bb + (size_t)gn * ldb + bc);
                *(uint4*)&Bl[br * 40 + bq2 * 8] = v;
            }
            __syncthreads();
            short8 a0 = *(const short8*)&Al[(wave * 32 + mlane) * 40 + koff];
            short8 a1 = *(const short8*)&Al[(wave * 32 + 16 + mlane) * 40 + koff];
#pragma unroll
            for (int ns = 0; ns < NS; ns++) {
                short8 bfr = *(const short8*)&Bl[(ns * 16 + mlane) * 40 + koff];
                acc[0][ns] = __builtin_amdgcn_mfma_f32_16x16x32_bf16(a0, bfr, acc[0][ns], 0, 0, 0);
                acc[1][ns] = __builtin_amdgcn_mfma_f32_16x16x32_bf16(a1, bfr, acc[1][ns], 0, 0, 0);
            }
            __syncthreads();
        }
    }

    float* Cz = C + (size_t)blockIdx.z * csplit;
#pragma unroll
    for (int ms = 0; ms < 2; ms++) {
#pragma unroll
        for (int ns = 0; ns < NS; ns++) {
            int n = n0 + ns * 16 + mlane;
            if (n >= N) continue;
#pragma unroll
            for (int r = 0; r < 4; r++) {
                int m = m0 + wave * 32 + ms * 16 + (lane >> 4) * 4 + r;
                int orow = m, ocol = n;
                if (CONVM == 2) {
                    int hh = (m >= Mhalf) ? 1 : 0;
                    orow = m - hh * Mhalf;
                    ocol = n + hh * choff;
                } else if (rowmap) {                 // (b*63+nn)*32+mm -> (b*32+mm)*63+nn
                    int bn = m >> 5, mm = m & 31;
                    int b = bn / Nq, nn = bn - b * Nq;
                    orow = (b * Mq + mm) * Nq + nn;
                }
                float v = acc[ms][ns][r];
                if (resid) v += resid[(size_t)orow * ldr + ocol];
                if (Cb) {
                    if (gsilu && ((ocol >> 8) & 1)) v = silu_f(v);   // pre-gate z cols
                    Cb[(size_t)orow * ldc + ocol] = __float2bfloat16(v);
                } else {
                    size_t o = (size_t)orow * ldc + ocol;
                    if (accum) Cz[o] += v; else Cz[o] = v;
                }
            }
        }
    }
}

// ============ fused dt_proj + softplus + scan + D skip + gate ============
template<int SLEN>
__global__ __launch_bounds__(256) void scan_k(bf16* __restrict__ xz2,
                                              const bf16* __restrict__ uc,
                                              const float* __restrict__ xd, int ldxd,
                                              const float* __restrict__ dtw,
                                              const float* __restrict__ dtb,
                                              const float* __restrict__ alog,
                                              const float* __restrict__ Dp,
                                              int nb, int dual) {
    int bid = blockIdx.x;
    int half = (dual && bid >= nb) ? 1 : 0;
    int row = bid - half * nb;
    int rev = half;
    int d = threadIdx.x;
    f32x2 h2[8];
#pragma unroll
    for (int j = 0; j < 8; j++) h2[j] = (f32x2){0.f, 0.f};
    const float* al = alog + half * 4096 + d * 16;
    float a0 = -__expf(al[0]);
    bool fast = true;
#pragma unroll
    for (int j = 1; j < 16; j++) {
        float aj = -__expf(al[j]);
        fast = fast && (fabsf(aj - a0 * (float)(j + 1)) < 1e-5f * (float)(j + 1));
    }
    f32x2 dw2[4];
#pragma unroll
    for (int r = 0; r < 4; r++)
        dw2[r] = (f32x2){dtw[half * 2048 + d * 8 + 2 * r], dtw[half * 2048 + d * 8 + 2 * r + 1]};
    float dbv = dtb[half * 256 + d], Dv = Dp[half * 256 + d];

    const float* xr = xd + (size_t)row * SLEN * ldxd + half * 40;
    size_t base  = (size_t)row * SLEN * 1024 + half * 512 + d;   // xz2 (y write, z read)
    size_t ubase = (size_t)row * SLEN * 512 + half * 256 + d;    // uc (conv'd u read)
    constexpr int NCH = (SLEN + 7) / 8;
    int dstep = rev ? -1 : 1;

    float ucur[8], zcur[8], unxt[8], znxt[8];
#pragma unroll
    for (int i = 0; i < 8; i++) {
        int st = i < SLEN ? i : SLEN - 1;
        int s = rev ? (SLEN - 1 - st) : st;
        ucur[i] = __bfloat162float(uc[ubase + (size_t)s * 512]);
        zcur[i] = __bfloat162float(xz2[base + (size_t)s * 1024 + 256]);  // silu(z)
    }
    float qb[2][40];
    {
        const float4* p = (const float4*)(xr + (size_t)(rev ? (SLEN - 1) : 0) * ldxd);
#pragma unroll
        for (int k = 0; k < 10; k++) *(float4*)&qb[0][k * 4] = p[k];
    }

    for (int c = 0; c < NCH; c++) {
        if (c + 1 < NCH) {
#pragma unroll
            for (int i = 0; i < 8; i++) {
                int st = (c + 1) * 8 + i; st = st < SLEN ? st : SLEN - 1;
                int s = rev ? (SLEN - 1 - st) : st;
                unxt[i] = __bfloat162float(uc[ubase + (size_t)s * 512]);
                znxt[i] = __bfloat162float(xz2[base + (size_t)s * 1024 + 256]);
            }
        }
#pragma unroll
        for (int i = 0; i < 8; i++) {
            int st = c * 8 + i;
            if (st < SLEN) {
                int s = rev ? (SLEN - 1 - st) : st;
                const float* q = qb[i & 1];
                if (st + 1 < SLEN) {
                    const float4* p = (const float4*)(xr + (size_t)(s + dstep) * ldxd);
#pragma unroll
                    for (int k = 0; k < 10; k++) *(float4*)&qb[(i + 1) & 1][k * 4] = p[k];
                }
                float uc_v = ucur[i];
                f32x2 acc2 = dw2[0] * (f32x2){q[0], q[1]};
                acc2 += dw2[1] * (f32x2){q[2], q[3]};
                acc2 += dw2[2] * (f32x2){q[4], q[5]};
                acc2 += dw2[3] * (f32x2){q[6], q[7]};
                float dtv = dbv + acc2.x + acc2.y;
                dtv = fmaxf(dtv, 0.f) + __logf(1.f + __expf(-fabsf(dtv)));   // softplus
                float du = dtv * uc_v;
                float y;
                if (fast) {
                    float p1 = __expf(dtv * a0);
                    float p2 = p1 * p1;
                    f32x2 pp = (f32x2){p2, p2};
                    f32x2 e2[8];
                    e2[0] = (f32x2){p1, p2};
#pragma unroll
                    for (int j = 1; j < 8; j++) e2[j] = e2[j - 1] * pp;
                    f32x2 du2 = (f32x2){du, du};
                    f32x2 y2 = (f32x2){0.f, 0.f};
#pragma unroll
                    for (int j = 0; j < 8; j++) {
                        f32x2 b2 = (f32x2){q[8 + 2 * j], q[9 + 2 * j]};
                        f32x2 c2 = (f32x2){q[24 + 2 * j], q[25 + 2 * j]};
                        h2[j] = h2[j] * e2[j] + du2 * b2;
                        y2 += h2[j] * c2;
                    }
                    y = y2.x + y2.y;
                } else {
                    y = 0.f;
#pragma unroll
                    for (int j = 0; j < 16; j++) {
                        float e = __expf(dtv * (-__expf(al[j])));
                        float hh = h2[j >> 1][j & 1];
                        hh = hh * e + du * q[8 + j];
                        h2[j >> 1][j & 1] = hh;
                        y += hh * q[24 + j];
                    }
                }
                xz2[base + (size_t)s * 1024] =
                    __float2bfloat16((y + uc_v * Dv) * zcur[i]);   // gate = 1 mul
            }
        }
#pragma unroll
        for (int i = 0; i < 8; i++) { ucur[i] = unxt[i]; zcur[i] = znxt[i]; }
    }
}

// ============ token mix + LN (bf16 hist, 4 rows/block) ============
__global__ __launch_bounds__(256) void mix_ln_tok(const bf16* __restrict__ hb,
                                                 float* __restrict__ mixb, bf16* __restrict__ lnb_out,
                                                 const float* __restrict__ alpha,
                                                 const float* __restrict__ beta,
                                                 const float* __restrict__ lnw,
                                                 const float* __restrict__ lnb, int l) {
    int t = blockIdx.x * 4 + (threadIdx.x >> 6), d = threadIdx.x & 63;
    int cnt = l + 1;
    float aw[4], bw[4];
    float amax = -1e30f, bmax = -1e30f;
    for (int i = 0; i < cnt; i++) {
        aw[i] = alpha[l * 4 + i]; bw[i] = beta[l * 4 + i];
        amax = fmaxf(amax, aw[i]); bmax = fmaxf(bmax, bw[i]);
    }
    float as = 0.f, bs = 0.f;
    for (int i = 0; i < cnt; i++) {
        aw[i] = __expf(aw[i] - amax); as += aw[i];
        bw[i] = __expf(bw[i] - bmax); bs += bw[i];
    }
    float ai = 1.f / as, bi = 1.f / bs;
    float v0 = 0.f, v1 = 0.f;
    for (int i = 0; i < cnt; i++) {
        const bf16* yt = hb + (size_t)(i == 0 ? 0 : i) * HSZB + (size_t)t * 128;
        const bf16* yc = hb + (size_t)(i == 0 ? 0 : 4 + i) * HSZB + (size_t)t * 128;
        float wa = aw[i] * ai, wb = bw[i] * bi;
        v0 += wa * __bfloat162float(yt[d])      + wb * __bfloat162float(yc[d]);
        v1 += wa * __bfloat162float(yt[d + 64]) + wb * __bfloat162float(yc[d + 64]);
    }
    float* mix = mixb + (size_t)t * 128;
    mix[d] = v0; mix[d + 64] = v1;
    float s = v0 + v1, ss = v0 * v0 + v1 * v1;
#pragma unroll
    for (int o = 32; o >= 1; o >>= 1) { s += __shfl_xor(s, o); ss += __shfl_xor(ss, o); }
    float mean = s * (1.f / 128.f);
    float var  = ss * (1.f / 128.f) - mean * mean;
    float rstd = rsqrtf(var + 1e-5f);
    bf16* lo = lnb_out + (size_t)t * 128;
    lo[d]      = __float2bfloat16((v0 - mean) * rstd * lnw[d]      + lnb[d]);
    lo[d + 64] = __float2bfloat16((v1 - mean) * rstd * lnw[d + 64] + lnb[d + 64]);
}

// ============ channel mix + LN + transpose (bf16 hist, 4 rows/block) ============
__global__ __launch_bounds__(256) void mix_ln_ch(const bf16* __restrict__ hb,
                                                float* __restrict__ mixb, bf16* __restrict__ lnb_out,
                                                const float* __restrict__ theta,
                                                const float* __restrict__ gamma,
                                                const float* __restrict__ lnw,
                                                const float* __restrict__ lnb, int l) {
    int t = blockIdx.x * 4 + (threadIdx.x >> 6), d = threadIdx.x & 63;
    int ct = l + 2, cg = l + 1;
    float tw[5], gw[4];
    float tmax = -1e30f, gmax = -1e30f;
    for (int i = 0; i < ct; i++) { tw[i] = theta[l * 5 + i]; tmax = fmaxf(tmax, tw[i]); }
    for (int i = 0; i < cg; i++) { gw[i] = gamma[l * 4 + i]; gmax = fmaxf(gmax, gw[i]); }
    float ts = 0.f, gs = 0.f;
    for (int i = 0; i < ct; i++) { tw[i] = __expf(tw[i] - tmax); ts += tw[i]; }
    for (int i = 0; i < cg; i++) { gw[i] = __expf(gw[i] - gmax); gs += gw[i]; }
    float ti = 1.f / ts, gi = 1.f / gs;
    float v0 = 0.f, v1 = 0.f;
    for (int i = 0; i < ct; i++) {
        const bf16* yt = hb + (size_t)(i == 0 ? 0 : i) * HSZB + (size_t)t * 128;
        float w_ = tw[i] * ti;
        v0 += w_ * __bfloat162float(yt[d]); v1 += w_ * __bfloat162float(yt[d + 64]);
    }
    for (int i = 0; i < cg; i++) {
        const bf16* yc = hb + (size_t)(i == 0 ? 0 : 4 + i) * HSZB + (size_t)t * 128;
        float w_ = gw[i] * gi;
        v0 += w_ * __bfloat162float(yc[d]); v1 += w_ * __bfloat162float(yc[d + 64]);
    }
    float* mix = mixb + (size_t)t * 128;
    mix[d] = v0; mix[d + 64] = v1;
    float s = v0 + v1, ss = v0 * v0 + v1 * v1;
#pragma unroll
    for (int o = 32; o >= 1; o >>= 1) { s += __shfl_xor(s, o); ss += __shfl_xor(ss, o); }
    float mean = s * (1.f / 128.f);
    float var  = ss * (1.f / 128.f) - mean * mean;
    float rstd = rsqrtf(var + 1e-5f);
    int bm = t / Nq, n = t - bm * Nq, b = bm >> 5, m = bm & 31;
    bf16* lo = lnb_out + (size_t)((b * Nq + n) * Mq + m) * 128;
    lo[d]      = __float2bfloat16((v0 - mean) * rstd * lnw[d]      + lnb[d]);
    lo[d + 64] = __float2bfloat16((v1 - mean) * rstd * lnw[d + 64] + lnb[d + 64]);
}

// ============ plain LN over D=128 (bf16 in, fp32 out, 4 rows/block) ============
__global__ __launch_bounds__(256) void ln128_kernel(const bf16* __restrict__ in,
                                                   const float* __restrict__ w,
                                                   const float* __restrict__ b,
                                                   float* __restrict__ out) {
    int t = blockIdx.x * 4 + (threadIdx.x >> 6), d = threadIdx.x & 63;
    float v0 = __bfloat162float(in[(size_t)t * 128 + d]);
    float v1 = __bfloat162float(in[(size_t)t * 128 + d + 64]);
    float s = v0 + v1, ss = v0 * v0 + v1 * v1;
#pragma unroll
    for (int o = 32; o >= 1; o >>= 1) { s += __shfl_xor(s, o); ss += __shfl_xor(ss, o); }
    float mean = s * (1.f / 128.f);
    float var  = ss * (1.f / 128.f) - mean * mean;
    float rstd = rsqrtf(var + 1e-5f);
    out[(size_t)t * 128 + d]      = (v0 - mean) * rstd * w[d]      + b[d];
    out[(size_t)t * 128 + d + 64] = (v1 - mean) * rstd * w[d + 64] + b[d + 64];
}

// ============ LN over N=63, bf16 out ============
__global__ __launch_bounds__(256) void final_ln2(const float* __restrict__ in,
                                                 const float* __restrict__ w2,
                                                 const float* __restrict__ b2,
                                                 bf16* __restrict__ out) {
    int idx = blockIdx.x * 256 + threadIdx.x;
    if (idx >= BMq * Dq) return;
    int bm = idx >> 7, d = idx & 127;
    float s = 0.f, ss = 0.f;
    for (int n = 0; n < Nq; n++) {
        float v = in[((size_t)bm * Nq + n) * 128 + d];
        s += v; ss += v * v;
    }
    float mean = s * (1.f / (float)Nq);
    float var  = ss * (1.f / (float)Nq) - mean * mean;
    float rstd = rsqrtf(var + 1e-5f);
    for (int n = 0; n < Nq; n++) {
        float v = in[((size_t)bm * Nq + n) * 128 + d];
        out[((size_t)bm * Nq + n) * 128 + d] = __float2bfloat16((v - mean) * rstd * w2[n] + b2[n]);
    }
}

// ============ final: split-K reduce + bias + rescale + transpose ============
__global__ __launch_bounds__(256) void finalize_kernel(const float* __restrict__ part,
                                                       const float* __restrict__ bias,
                                                       const float* __restrict__ means,
                                                       const float* __restrict__ stds,
                                                       float* __restrict__ out) {
    int idx = blockIdx.x * 256 + threadIdx.x;
    if (idx >= Bq * PREDq * Mq) return;
    int b = idx / (PREDq * Mq);
    int r = idx - b * PREDq * Mq;
    int pr = r >> 5, m = r & 31;
    int bm = b * Mq + m;
    float s = bias[pr];
#pragma unroll
    for (int z = 0; z < 12; z++) s += part[(size_t)z * BMq * PREDq + (size_t)bm * PREDq + pr];
    out[idx] = s * stds[bm] + means[bm];
}

extern "C" void kernel_launch(void* const* d_in, const int* in_sizes, int n_in,
                              void* d_out, int out_size, void* d_ws, size_t ws_size,
                              hipStream_t stream) {
    if (ws_size < WS_FLOATS * sizeof(float)) return;

    const float* x          = (const float*)d_in[0];
    const float* patch_w    = (const float*)d_in[1];
    const float* patch_b    = (const float*)d_in[2];
    const float* pos_embed  = (const float*)d_in[3];
    const float* alpha      = (const float*)d_in[4];
    const float* beta       = (const float*)d_in[5];
    const float* theta      = (const float*)d_in[6];
    const float* gamma      = (const float*)d_in[7];
    const float* tok_norm_w = (const float*)d_in[8];
    const float* tok_norm_b = (const float*)d_in[9];
    const float* ch_norm_w  = (const float*)d_in[10];
    const float* ch_norm_b  = (const float*)d_in[11];
    const float* in_proj_w  = (const float*)d_in[12];
    const float* conv_w     = (const float*)d_in[13];
    const float* conv_b     = (const float*)d_in[14];
    const float* x_proj_w   = (const float*)d_in[15];
    const float* dt_proj_w  = (const float*)d_in[16];
    const float* dt_proj_b  = (const float*)d_in[17];
    const float* A_log      = (const float*)d_in[18];
    const float* D_ssm      = (const float*)d_in[19];
    const float* out_proj_w = (const float*)d_in[20];
    const float* n2d_w1     = (const float*)d_in[21];
    const float* n2d_b1     = (const float*)d_in[22];
    const float* n2d_w2     = (const float*)d_in[23];
    const float* n2d_b2     = (const float*)d_in[24];
    const float* head_w     = (const float*)d_in[25];
    const float* head_b     = (const float*)d_in[26];

    float* W   = (float*)d_ws;
    float* out = (float*)d_out;
    bf16* WB   = (bf16*)(W + OFF_WB);
    bf16* HB   = (bf16*)(W + OFF_HISTB);
    bf16* LNB  = (bf16*)(W + OFF_LNB);
    bf16* XZ2  = (bf16*)(W + OFF_XZ2);
    bf16* UC   = (bf16*)(W + OFF_UC);
    float* XD  = W + OFF_XD;
    float* MIX = W + OFF_MIX;

    f2b_all<<<(WB_TOTAL + 255) / 256, 256, 0, stream>>>(
        in_proj_w, x_proj_w, out_proj_w, head_w, WB);

    stats_kernel<<<BMq, 256, 0, stream>>>(x, W + OFF_MEANS, W + OFF_STDS);
    patch_embed<<<TOKq, 128, 0, stream>>>(x, W + OFF_MEANS, W + OFF_STDS,
                                          patch_w, patch_b, pos_embed, HB);

    for (int l = 0; l < NLq; l++) {
        size_t o0 = (size_t)(l * 3 + 0), o1 = (size_t)(l * 3 + 1), o2 = (size_t)(l * 3 + 2);

        // ================= token mamba =================
        mix_ln_tok<<<TOKq / 4, 256, 0, stream>>>(HB, MIX, LNB, alpha, beta,
                                                 tok_norm_w + l * Dq, tok_norm_b + l * Dq, l);
        gemm_k<0, 0, 128><<<dim3(4, 252, 1), 256, 0, stream>>>(
            LNB, 128, WB + WBE_IN + o0 * 65536, nullptr, 128, nullptr, 0,
            nullptr, XZ2, 1024, TOKq, 512, 128, 0, 0, 0, 0,
            0, nullptr, nullptr, 0, 0, 0, 1, nullptr);
        gemm_k<1, 0, 64><<<dim3(1, 252, 1), 256, 0, stream>>>(
            XZ2, 1024, WB + WBE_X + o0 * 10240, nullptr, 256, nullptr, 0,
            XD, nullptr, 40, TOKq, 40, 256, 0, 0, 0, 0,
            Nq, conv_w + o0 * 1024, conv_b + o0 * 256, 0, 0, 0, 0, UC);
        scan_k<Nq><<<BMq, 256, 0, stream>>>(
            XZ2, UC, XD, 40, dt_proj_w + o0 * 2048, dt_proj_b + o0 * 256,
            A_log + o0 * 4096, D_ssm + o0 * 256, BMq, 0);
        gemm_k<0, 0, 64><<<dim3(2, 252, 1), 256, 0, stream>>>(
            XZ2, 1024, WB + WBE_OUT + o0 * 32768, nullptr, 256, MIX, 128,
            nullptr, HB + (size_t)(1 + l) * HSZB, 128,
            TOKq, 128, 256, 0, 0, 0, 0, 0, nullptr, nullptr, 0, 0, 0, 0, nullptr);

        // ================= channel mamba (fwd+bwd merged) =================
        mix_ln_ch<<<TOKq / 4, 256, 0, stream>>>(HB, MIX, LNB, theta, gamma,
                                                ch_norm_w + l * Dq, ch_norm_b + l * Dq, l);
        gemm_k<0, 0, 128><<<dim3(8, 252, 1), 256, 0, stream>>>(
            LNB, 128, WB + WBE_IN + o1 * 65536, nullptr, 128, nullptr, 0,
            nullptr, XZ2, 1024, TOKq, 1024, 128, 0, 0, 0, 0,
            0, nullptr, nullptr, 0, 0, 0, 1, nullptr);
        gemm_k<2, 0, 64><<<dim3(1, 504, 1), 256, 0, stream>>>(
            XZ2, 1024, WB + WBE_X + o1 * 10240, WB + WBE_X + o2 * 10240, 256,
            nullptr, 0, XD, nullptr, 80, 2 * TOKq, 40, 256, 0, 0, 0, 0,
            Mq, conv_w + o1 * 1024, conv_b + o1 * 256, TOKq, 512, 40, 0, UC);
        scan_k<Mq><<<2 * BNq, 256, 0, stream>>>(
            XZ2, UC, XD, 80, dt_proj_w + o1 * 2048, dt_proj_b + o1 * 256,
            A_log + o1 * 4096, D_ssm + o1 * 256, BNq, 1);
        gemm_k<0, 1, 64><<<dim3(2, 252, 1), 256, 0, stream>>>(
            XZ2, 1024, WB + WBE_OUT + o1 * 32768, WB + WBE_OUT + o2 * 32768, 256,
            MIX, 128, nullptr, HB + (size_t)(5 + l) * HSZB, 128,
            TOKq, 128, 512, 0, 0, 0, 1, 0, nullptr, nullptr, 0, 0, 0, 0, nullptr);
    }

    // ---- Norm2D + head ----
    ln128_kernel<<<TOKq / 4, 256, 0, stream>>>(HB + 8 * HSZB, n2d_w1, n2d_b1, MIX);
    final_ln2<<<(BMq * Dq + 255) / 256, 256, 0, stream>>>(MIX, n2d_w2, n2d_b2, LNB);
    gemm_k<0, 0, 64><<<dim3(2, 4, 12), 256, 0, stream>>>(
        LNB, Nq * Dq, WB + WBE_HEAD, nullptr, Nq * Dq, nullptr, 0,
        W + OFF_PART, nullptr, PREDq, BMq, PREDq, 672, 672,
        (size_t)BMq * PREDq, 0, 0, 0, nullptr, nullptr, 0, 0, 0, 0, nullptr);
    finalize_kernel<<<(Bq * PREDq * Mq + 255) / 256, 256, 0, stream>>>(
        W + OFF_PART, head_b, W + OFF_MEANS, W + OFF_STDS, out);
}